// Round 4
// baseline (1141.754 us; speedup 1.0000x reference)
//
#include <hip/hip_runtime.h>

#define E_DIM   2048
#define NHEADS  16
#define NBATCH  4
#define SLEN    2048
#define TLEN    2048
#define DHEAD   128
#define MROWS   (NBATCH * SLEN)   // 8192

typedef __bf16  bf16x8  __attribute__((ext_vector_type(8)));
typedef float   floatx4 __attribute__((ext_vector_type(4)));
typedef unsigned short ushort8_v __attribute__((ext_vector_type(8)));

__device__ __forceinline__ unsigned short f2bf(float f) {
    unsigned int u = __builtin_bit_cast(unsigned int, f);
    u = (u + 0x7fffu + ((u >> 16) & 1u)) >> 16;
    return (unsigned short)u;
}
__device__ __forceinline__ unsigned int f2bf2(float a, float b) {
    return (unsigned int)f2bf(a) | ((unsigned int)f2bf(b) << 16);
}

// async global->LDS, 16 B per lane: LDS dest = wave-uniform base + lane*16
__device__ __forceinline__ void gload16(const unsigned short* g, unsigned short* l) {
    __builtin_amdgcn_global_load_lds(
        (const __attribute__((address_space(1))) unsigned int*)(const void*)g,
        (__attribute__((address_space(3))) unsigned int*)(void*)l, 16, 0, 0);
}

// ---------------------------------------------------------------------------
// fp32 -> bf16 conversion kernels
// ---------------------------------------------------------------------------
__global__ __launch_bounds__(256)
void conv_qkv(const float* __restrict__ q, const float* __restrict__ k,
              const float* __restrict__ v, unsigned short* __restrict__ dst)
{
    const float* src = (blockIdx.y == 0) ? q : ((blockIdx.y == 1) ? k : v);
    const size_t base = (size_t)blockIdx.y * ((size_t)MROWS * E_DIM);
    const size_t i = ((size_t)blockIdx.x * 256 + threadIdx.x) * 8;
    const float4 a = *(const float4*)(src + i);
    const float4 b = *(const float4*)(src + i + 4);
    ushort8_v o;
    o[0]=f2bf(a.x); o[1]=f2bf(a.y); o[2]=f2bf(a.z); o[3]=f2bf(a.w);
    o[4]=f2bf(b.x); o[5]=f2bf(b.y); o[6]=f2bf(b.z); o[7]=f2bf(b.w);
    *(ushort8_v*)(dst + base + i) = o;
}

__global__ __launch_bounds__(256)
void conv_w(const float* __restrict__ w0, const float* __restrict__ w1,
            const float* __restrict__ w2, const float* __restrict__ w3,
            unsigned short* __restrict__ dst)
{
    const float* src = (blockIdx.y == 0) ? w0 : ((blockIdx.y == 1) ? w1 :
                       ((blockIdx.y == 2) ? w2 : w3));
    const size_t base = (size_t)blockIdx.y * ((size_t)E_DIM * E_DIM);
    const size_t i = ((size_t)blockIdx.x * 256 + threadIdx.x) * 8;
    const float4 a = *(const float4*)(src + i);
    const float4 b = *(const float4*)(src + i + 4);
    ushort8_v o;
    o[0]=f2bf(a.x); o[1]=f2bf(a.y); o[2]=f2bf(a.z); o[3]=f2bf(a.w);
    o[4]=f2bf(b.x); o[5]=f2bf(b.y); o[6]=f2bf(b.z); o[7]=f2bf(b.w);
    *(ushort8_v*)(dst + base + i) = o;
}

// ---------------------------------------------------------------------------
// GEMM: C[M,Nd] = (A[M,K] * B[Nd,K]^T + bias) * scale. A,B bf16. m97 pattern.
// 1-D grid of 1024 blocks, XCD-swizzled: li%8 = XCD; each XCD owns 8 bm-panels
// x 16 bn-tiles -> A-panel fetched on one XCD only, B shared in its L2.
// EPI: 0 = fp32 std layout, 1 = bf16 std layout, 2 = bf16 direct-V^T layout.
// ---------------------------------------------------------------------------
template<int EPI>
__global__ __launch_bounds__(256, 2)
void gemm_bt(const unsigned short* __restrict__ A, const unsigned short* __restrict__ B,
             const float* __restrict__ bias, void* __restrict__ Cv,
             int M, int Nd, int K, float scale)
{
    __shared__ unsigned short As[128 * 32];
    __shared__ unsigned short Bs[128 * 32];

    const int tid  = threadIdx.x;
    const int li   = blockIdx.x;                  // 0..1023 (M=8192, Nd=2048)
    const int bm   = ((li >> 7) * 8 + (li & 7)) * 128;   // 64 bm panels
    const int bn   = ((li >> 3) & 15) * 128;             // 16 bn tiles
    const int wave = tid >> 6, lane = tid & 63;
    const int wm   = (wave >> 1) * 64, wn = (wave & 1) * 64;
    const int lrow = lane & 15, quad = lane >> 4;

    // staging lane mapping: row = lane/4, physical chunk = lane%4
    const int srow = lane >> 2, schk = lane & 3;
    const int slog = schk ^ ((srow >> 1) & 3);           // logical chunk in global
    const unsigned short* ag = A + (size_t)(bm + wave * 32 + srow) * K + slog * 8;
    const unsigned short* bg = B + (size_t)(bn + wave * 32 + srow) * K + slog * 8;
    unsigned short* lA0 = &As[(wave * 32) * 32];
    unsigned short* lA1 = &As[(wave * 32 + 16) * 32];
    unsigned short* lB0 = &Bs[(wave * 32) * 32];
    unsigned short* lB1 = &Bs[(wave * 32 + 16) * 32];

    const int aswz = (quad ^ ((lrow >> 1) & 3)) * 8;     // read-side physical chunk

    floatx4 acc[4][4] = {};

    for (int k0 = 0; k0 < K; k0 += 32) {
        gload16(ag + k0,                  lA0);
        gload16(ag + (size_t)16 * K + k0, lA1);
        gload16(bg + k0,                  lB0);
        gload16(bg + (size_t)16 * K + k0, lB1);
        __syncthreads();   // drains vmcnt -> staged data visible

        bf16x8 af[4], bfr[4];
        #pragma unroll
        for (int mi = 0; mi < 4; ++mi)
            af[mi] = *(const bf16x8*)&As[(wm + mi * 16 + lrow) * 32 + aswz];
        #pragma unroll
        for (int ni = 0; ni < 4; ++ni)
            bfr[ni] = *(const bf16x8*)&Bs[(wn + ni * 16 + lrow) * 32 + aswz];
        #pragma unroll
        for (int mi = 0; mi < 4; ++mi)
            #pragma unroll
            for (int ni = 0; ni < 4; ++ni)
                acc[mi][ni] = __builtin_amdgcn_mfma_f32_16x16x32_bf16(af[mi], bfr[ni], acc[mi][ni], 0, 0, 0);
        __syncthreads();
    }

    // epilogue: C/D layout col=lane&15, row=quad*4+i
    #pragma unroll
    for (int ni = 0; ni < 4; ++ni) {
        const int col = bn + wn + ni * 16 + lrow;
        const float bv = bias[col];
        #pragma unroll
        for (int mi = 0; mi < 4; ++mi) {
            const int row = bm + wm + mi * 16 + quad * 4;
            if constexpr (EPI == 2) {
                // write V^T directly: (N,T,E)[row=(n,t), col=(h,d)] -> Vt(N,H,D,T)
                const int n = row >> 11, t = row & 2047;
                const int hh = col >> 7, dd = col & 127;
                unsigned short* dst = (unsigned short*)Cv +
                    (((size_t)(n * 16 + hh) * 128 + dd) * 2048 + t);
                ushort4 w;
                w.x = f2bf((acc[mi][ni][0] + bv) * scale);
                w.y = f2bf((acc[mi][ni][1] + bv) * scale);
                w.z = f2bf((acc[mi][ni][2] + bv) * scale);
                w.w = f2bf((acc[mi][ni][3] + bv) * scale);
                *(ushort4*)dst = w;   // 4 consecutive t, 8B aligned
            } else {
                #pragma unroll
                for (int i = 0; i < 4; ++i) {
                    const float v = (acc[mi][ni][i] + bv) * scale;
                    if constexpr (EPI == 1)
                        ((unsigned short*)Cv)[(size_t)(row + i) * Nd + col] = f2bf(v);
                    else
                        ((float*)Cv)[(size_t)(row + i) * Nd + col] = v;
                }
            }
        }
    }
}

// ---------------------------------------------------------------------------
// Mask tile summary: per 128x128 tile of mask[T,S]: 0=all-zero, 1=mixed, 2=all-ones
// ---------------------------------------------------------------------------
__global__ __launch_bounds__(256)
void mask_tiles(const int* __restrict__ mask, unsigned char* __restrict__ flags)
{
    __shared__ int s_and, s_or;
    const int tid = threadIdx.x;
    if (tid == 0) { s_and = 1; s_or = 0; }
    __syncthreads();
    const int tt = blockIdx.x >> 4;
    const int ss = blockIdx.x & 15;
    int la = 1, lo = 0;
    #pragma unroll
    for (int it = 0; it < 16; ++it) {
        const int c = it * 256 + tid;
        const int row = c >> 5, c4 = c & 31;
        const int4 v = *(const int4*)(mask + (size_t)(tt * 128 + row) * SLEN + ss * 128 + c4 * 4);
        const int nz = (v.x != 0) + (v.y != 0) + (v.z != 0) + (v.w != 0);
        la &= (nz == 4); lo |= (nz != 0);
    }
    if (!la) atomicAnd(&s_and, 0);
    if (lo)  atomicOr(&s_or, 1);
    __syncthreads();
    if (tid == 0) flags[blockIdx.x] = (unsigned char)(s_and ? 2 : (s_or ? 1 : 0));
}

// ---------------------------------------------------------------------------
// Flash attention, transposed scores AND transposed output.
// Q pre-scaled by (1/sqrt(d))*log2(e).
// S^T = K*Q^T -> lane holds [t=ti*16+quad*4+i][s=si*16+lrow].
// O^T = V*P^T (A=Vs rows [d][t], B=Ps rows [s][t]) -> lane holds
// [d=di*16+quad*4+i][s=si*16+lrow]: stats index (s=lrow) == accumulator col
// -> zero broadcast shuffles; i-register = consecutive d -> ushort4 O stores.
// 1-D grid, XCD-swizzled: all 16 s-tiles of one (n,h) on one XCD -> K/V from L2.
// ---------------------------------------------------------------------------
#define LDK  136   // K/V tile row stride (272 B, 16B-aligned)
#define LDP2 40    // P chunk row stride (80 B)

__global__ __launch_bounds__(256, 2)
void flash_attn(const unsigned short* __restrict__ Q,
                const unsigned short* __restrict__ Kb,
                const unsigned short* __restrict__ Vt,
                const int* __restrict__ mask,
                const unsigned char* __restrict__ tflags,
                unsigned short* __restrict__ O)
{
    __shared__ unsigned short Ks[128 * LDK];
    __shared__ unsigned short Vs[128 * LDK];
    __shared__ unsigned short Ps[4][32 * LDP2];

    const int tid  = threadIdx.x;
    const int li   = blockIdx.x;          // 0..1023
    const int xcd  = li & 7;
    const int jj   = li >> 3;             // 0..127
    const int g    = (jj >> 4) * 8 + xcd; // head group 0..63, fixed per XCD
    const int s0   = (jj & 15) * 128;     // s-tile within group
    const int h    = g & 15, n = g >> 4;
    const int wave = tid >> 6, lane = tid & 63;
    const int lrow = lane & 15, quad = lane >> 4;
    const int qbase = s0 + wave * 32;

    // Q fragments (B-operand layout: n=lane&15, k=quad*8+j)
    bf16x8 aq[2][4];
    #pragma unroll
    for (int si = 0; si < 2; ++si)
        #pragma unroll
        for (int kk = 0; kk < 4; ++kk)
            aq[si][kk] = *(const bf16x8*)(Q + ((size_t)(n * SLEN + qbase + si * 16 + lrow) * NHEADS + h) * DHEAD
                                            + kk * 32 + quad * 8);

    float m_r[2] = { -INFINITY, -INFINITY };   // stats for s = si*16 + lrow
    float l_r[2] = { 0.f, 0.f };
    floatx4 occ[8][2] = {};                    // O^T: [d=di*16+quad*4+i][s=si*16+lrow]

    for (int t0 = 0; t0 < TLEN; t0 += 128) {
        const int flag = tflags[(t0 >> 7) * (SLEN >> 7) + (s0 >> 7)];
        if (flag == 0) continue;   // uniform per block

        // stage K tile [t][d] and V^T tile [d][t]
        #pragma unroll
        for (int it = 0; it < 8; ++it) {
            const int c = it * 256 + tid;
            const int row = c >> 4, c16 = c & 15;
            *(ushort8_v*)&Ks[row * LDK + c16 * 8] =
                *(const ushort8_v*)(Kb + ((size_t)(n * TLEN + t0 + row) * NHEADS + h) * DHEAD + c16 * 8);
            *(ushort8_v*)&Vs[row * LDK + c16 * 8] =
                *(const ushort8_v*)(Vt + ((size_t)(n * NHEADS + h) * DHEAD + row) * TLEN + t0 + c16 * 8);
        }
        __syncthreads();

        // S^T = K * Q^T : D[m=t][n=s]
        floatx4 sacc[8][2] = {};
        #pragma unroll
        for (int kk = 0; kk < 4; ++kk)
            #pragma unroll
            for (int ti = 0; ti < 8; ++ti) {
                const bf16x8 ak = *(const bf16x8*)&Ks[(ti * 16 + lrow) * LDK + kk * 32 + quad * 8];
                sacc[ti][0] = __builtin_amdgcn_mfma_f32_16x16x32_bf16(ak, aq[0][kk], sacc[ti][0], 0, 0, 0);
                sacc[ti][1] = __builtin_amdgcn_mfma_f32_16x16x32_bf16(ak, aq[1][kk], sacc[ti][1], 0, 0, 0);
            }

        if (flag == 1) {
            #pragma unroll
            for (int ti = 0; ti < 8; ++ti)
                #pragma unroll
                for (int si = 0; si < 2; ++si)
                    #pragma unroll
                    for (int i = 0; i < 4; ++i) {
                        const int t = t0 + ti * 16 + quad * 4 + i;
                        const int s = s0 + wave * 32 + si * 16 + lrow;
                        if (mask[(size_t)t * SLEN + s] == 0) sacc[ti][si][i] = -INFINITY;
                    }
        }

        // row stats: in-lane over (ti,i), then across quads (xor 16, 32)
        float mt[2];
        #pragma unroll
        for (int si = 0; si < 2; ++si) {
            float v = sacc[0][si][0];
            #pragma unroll
            for (int ti = 0; ti < 8; ++ti)
                #pragma unroll
                for (int i = 0; i < 4; ++i) v = fmaxf(v, sacc[ti][si][i]);
            v = fmaxf(v, __shfl_xor(v, 16));
            v = fmaxf(v, __shfl_xor(v, 32));
            mt[si] = v;
        }

        float alpha[2];
        #pragma unroll
        for (int si = 0; si < 2; ++si) {
            const float mnew = fmaxf(m_r[si], mt[si]);
            alpha[si] = (mnew == -INFINITY) ? 0.f : exp2f(m_r[si] - mnew);
            m_r[si] = mnew;
        }
        // rescale O accumulator (stats already in accumulator col layout)
        #pragma unroll
        for (int di = 0; di < 8; ++di)
            #pragma unroll
            for (int si = 0; si < 2; ++si)
                #pragma unroll
                for (int i = 0; i < 4; ++i)
                    occ[di][si][i] *= alpha[si];

        // fused exp + P-chunk staging + PV (per-wave Ps: same-wave DS ordering)
        float psum[2] = { 0.f, 0.f };
        #pragma unroll
        for (int kk = 0; kk < 4; ++kk) {
            #pragma unroll
            for (int si = 0; si < 2; ++si)
                #pragma unroll
                for (int half = 0; half < 2; ++half) {
                    const int ti = kk * 2 + half;
                    float p[4];
                    #pragma unroll
                    for (int i = 0; i < 4; ++i) {
                        const float e = exp2f(sacc[ti][si][i] - m_r[si]);
                        p[i] = (m_r[si] == -INFINITY) ? 0.f : e;
                    }
                    psum[si] += (p[0] + p[1]) + (p[2] + p[3]);
                    uint2 w;
                    w.x = f2bf2(p[0], p[1]);
                    w.y = f2bf2(p[2], p[3]);
                    *(uint2*)&Ps[wave][(si * 16 + lrow) * LDP2 + half * 16 + quad * 4] = w;
                }
            bf16x8 ap[2];
            #pragma unroll
            for (int si = 0; si < 2; ++si)
                ap[si] = *(const bf16x8*)&Ps[wave][(si * 16 + lrow) * LDP2 + quad * 8];
            #pragma unroll
            for (int di = 0; di < 8; ++di) {
                const bf16x8 av = *(const bf16x8*)&Vs[(di * 16 + lrow) * LDK + kk * 32 + quad * 8];
                occ[di][0] = __builtin_amdgcn_mfma_f32_16x16x32_bf16(av, ap[0], occ[di][0], 0, 0, 0);
                occ[di][1] = __builtin_amdgcn_mfma_f32_16x16x32_bf16(av, ap[1], occ[di][1], 0, 0, 0);
            }
        }

        #pragma unroll
        for (int si = 0; si < 2; ++si) {
            psum[si] += __shfl_xor(psum[si], 16);
            psum[si] += __shfl_xor(psum[si], 32);
            l_r[si] = l_r[si] * alpha[si] + psum[si];
        }
        __syncthreads();
    }

    // normalize and store O (N,S,H,D) bf16: lane has 4 consecutive d -> ushort4
    float rl[2];
    #pragma unroll
    for (int si = 0; si < 2; ++si)
        rl[si] = (l_r[si] > 0.f) ? 1.0f / l_r[si] : 0.f;

    #pragma unroll
    for (int di = 0; di < 8; ++di)
        #pragma unroll
        for (int si = 0; si < 2; ++si) {
            const int s  = s0 + wave * 32 + si * 16 + lrow;
            const int d0 = di * 16 + quad * 4;
            ushort4 w;
            w.x = f2bf(occ[di][si][0] * rl[si]);
            w.y = f2bf(occ[di][si][1] * rl[si]);
            w.z = f2bf(occ[di][si][2] * rl[si]);
            w.w = f2bf(occ[di][si][3] * rl[si]);
            *(ushort4*)(O + ((size_t)(n * SLEN + s) * NHEADS + h) * DHEAD + d0) = w;
        }
}

// ---------------------------------------------------------------------------
extern "C" void kernel_launch(void* const* d_in, const int* in_sizes, int n_in,
                              void* d_out, int out_size, void* d_ws, size_t ws_size,
                              hipStream_t stream)
{
    const float* query = (const float*)d_in[0];
    const float* key   = (const float*)d_in[1];
    const float* value = (const float*)d_in[2];
    const int*   mask  = (const int*)d_in[3];
    const float* Wq = (const float*)d_in[4];  const float* bq = (const float*)d_in[5];
    const float* Wk = (const float*)d_in[6];  const float* bk = (const float*)d_in[7];
    const float* Wv = (const float*)d_in[8];  const float* bv = (const float*)d_in[9];
    const float* Wp = (const float*)d_in[10]; const float* bp = (const float*)d_in[11];
    float* out = (float*)d_out;

    // ws layout (128 MB + 256 B): [Wb 32MB][A 32MB][B 32MB][C 32MB][flags]
    char* ws = (char*)d_ws;
    const size_t SLOT = 32ull * 1024 * 1024;
    unsigned short* Wb  = (unsigned short*)ws;              // 4 bf16 weights
    unsigned short* Abf = (unsigned short*)(ws + SLOT);     // q_bf -> later V^T
    unsigned short* Bbf = (unsigned short*)(ws + 2 * SLOT); // k_bf
    unsigned short* Cbf = (unsigned short*)(ws + 3 * SLOT); // v_bf -> later attn out
    unsigned char*  flags = (unsigned char*)(ws + 4 * SLOT);
    // Q/K projections parked in d_out (64 MB, dead before final GEMM writes it)
    unsigned short* Qb  = (unsigned short*)d_out;
    unsigned short* Kbb = (unsigned short*)((char*)d_out + SLOT);

    const size_t WSLOT = (size_t)E_DIM * E_DIM;
    const float sc = 0.08838834764831845f * 1.4426950408889634f; // 1/sqrt(128)*log2(e)

    mask_tiles<<<256, 256, 0, stream>>>(mask, flags);
    conv_qkv<<<dim3(8192, 3), 256, 0, stream>>>(query, key, value, Abf);
    conv_w<<<dim3(2048, 4), 256, 0, stream>>>(Wq, Wk, Wv, Wp, Wb);

    gemm_bt<1><<<1024, 256, 0, stream>>>(Abf, Wb,             bq, Qb,  MROWS, E_DIM, E_DIM, sc);
    gemm_bt<1><<<1024, 256, 0, stream>>>(Bbf, Wb + WSLOT,     bk, Kbb, MROWS, E_DIM, E_DIM, 1.f);
    gemm_bt<2><<<1024, 256, 0, stream>>>(Cbf, Wb + 2 * WSLOT, bv, Abf, MROWS, E_DIM, E_DIM, 1.f);
    flash_attn<<<1024, 256, 0, stream>>>(Qb, Kbb, Abf, mask, flags, Cbf);
    gemm_bt<0><<<1024, 256, 0, stream>>>(Cbf, Wb + 3 * WSLOT, bp, out, MROWS, E_DIM, E_DIM, 1.f);
}